// Round 3
// baseline (32721.356 us; speedup 1.0000x reference)
//
#include <hip/hip_runtime.h>
#include <math.h>

// Seq2seq LSTM: 5-layer stack, HID=80, 336 enc + 48 dec steps.
// Batch-split persistent blocks (NB=4/block, h/c in LDS).
// R3: R2's register-rotating weight prefetch with the DOT4 macro shadowing
//     bug fixed (inner pointer renamed _hb; R2 self-initialized `hb` = UB/NaN).
#define LAYERS 5
#define HID    80
#define GATES  320      // 4*HID, order [i|f|g|o]
#define INDIM  4
#define BATCH  512
#define SEQLEN 336
#define PREDLEN 48
#define NB     4        // batch elems per block
#define NTHR   320      // one thread per gate row; also == NB*HID for updates
#define NCHUNK 20       // HID/4 float4 chunks per weight row

static_assert(NTHR == GATES, "one thread per gate row");
static_assert(NTHR == NB * HID, "update mapping must cover NB*HID");
static_assert(NCHUNK * 4 == HID, "chunking");

__device__ __forceinline__ float sigm(float v) { return 1.0f / (1.0f + __expf(-v)); }
// tanh(x) = 1 - 2/(1+e^{2x}); abs err ~1e-7, saturates correctly at +-1.
__device__ __forceinline__ float tanh_fast(float v) { return 1.0f - 2.0f / (1.0f + __expf(2.0f * v)); }

// 16 FMAs: one float4 weight chunk against 4 batches' h[k..k+3] (LDS broadcast reads)
// NOTE: internal pointer is _hb — must not collide with caller locals (R2 bug).
#define DOT4(W, HBASE, K)                                                        \
    do {                                                                         \
        const float* _hb = (HBASE);                                              \
        const float4 h0 = *(const float4*)&_hb[0 * HID + (K)];                   \
        const float4 h1 = *(const float4*)&_hb[1 * HID + (K)];                   \
        const float4 h2 = *(const float4*)&_hb[2 * HID + (K)];                   \
        const float4 h3 = *(const float4*)&_hb[3 * HID + (K)];                   \
        a0 += (W).x * h0.x + (W).y * h0.y + (W).z * h0.z + (W).w * h0.w;         \
        a1 += (W).x * h1.x + (W).y * h1.y + (W).z * h1.z + (W).w * h1.w;         \
        a2 += (W).x * h2.x + (W).y * h2.y + (W).z * h2.z + (W).w * h2.w;         \
        a3 += (W).x * h3.x + (W).y * h3.y + (W).z * h3.z + (W).w * h3.w;         \
    } while (0)

__global__ __launch_bounds__(NTHR, 1) void lstm_s2s(
    const float* __restrict__ x,    const float* __restrict__ ff,
    const float* __restrict__ eW0,  const float* __restrict__ eWih,
    const float* __restrict__ eWhh, const float* __restrict__ ebih,
    const float* __restrict__ ebhh,
    const float* __restrict__ dW0,  const float* __restrict__ dWih,
    const float* __restrict__ dWhh, const float* __restrict__ dbih,
    const float* __restrict__ dbhh,
    const float* __restrict__ fcW,  const float* __restrict__ fcb,
    float* __restrict__ out)
{
    __shared__ __align__(16) float sh[LAYERS][NB][HID];   // hidden state
    __shared__ __align__(16) float sc[LAYERS][NB][HID];   // cell state
    __shared__ __align__(16) float sg[NB][GATES];         // activated gates
    __shared__ __align__(16) float sx[NB][INDIM];         // step input / dec feedback

    const int tid = threadIdx.x;
    const int g   = tid;
    const int b0  = blockIdx.x * NB;

    for (int i = tid; i < LAYERS * NB * HID; i += NTHR) {
        (&sh[0][0][0])[i] = 0.0f;
        (&sc[0][0][0])[i] = 0.0f;
    }

    const bool is_tanh_gate = (g >= 2 * HID) && (g < 3 * HID);
    const int  unb          = tid / HID;
    const int  uj           = tid % HID;

    // bias sums preloaded: [enc/dec][layer]
    float bsum[2][LAYERS];
    #pragma unroll
    for (int l = 0; l < LAYERS; ++l) {
        bsum[0][l] = ebih[l * GATES + g] + ebhh[l * GATES + g];
        bsum[1][l] = dbih[l * GATES + g] + dbhh[l * GATES + g];
    }

    // register-resident weight rows for the CURRENT stage
    float4 wih[NCHUNK];   // Wih row (l>0 stages)
    float4 whh[NCHUNK];   // Whh row
    float4 w0buf;         // W0 row (l==0 stages)

    // initial prefetch for stage (t=0, l=0)
    w0buf = *(const float4*)&eW0[g * INDIM];
    #pragma unroll
    for (int i = 0; i < NCHUNK; ++i)
        whh[i] = *(const float4*)&eWhh[(size_t)g * HID + 4 * i];

    for (int t = 0; t < SEQLEN + PREDLEN; ++t) {
        const bool enc = (t < SEQLEN);

        if (enc && tid < NB * INDIM) {
            const int nb = tid / INDIM, k = tid % INDIM;
            sx[nb][k] = x[((size_t)(b0 + nb) * SEQLEN + t) * INDIM + k];
        }
        __syncthreads();   // sx staged / dec feedback visible

        for (int l = 0; l < LAYERS; ++l) {
            // ---- next-stage weight pointers (for prefetch) ----
            int nl = l + 1, nt = t;
            if (nl == LAYERS) { nl = 0; ++nt; }
            const bool nenc    = (nt < SEQLEN);
            const bool valid_n = (nt < SEQLEN + PREDLEN);
            const float* nWih = (nl > 0)
                ? ((nenc ? eWih : dWih) + ((size_t)(nl - 1) * GATES + g) * HID)
                : nullptr;
            const float* nWhh = valid_n
                ? ((nenc ? eWhh : dWhh) + ((size_t)nl * GATES + g) * HID)
                : (eWhh + (size_t)g * HID);   // clamp: loaded but unused
            const float* nW0  = (nl == 0 && valid_n) ? ((nenc ? eW0 : dW0) + g * INDIM)
                                                     : nullptr;

            const float bias = enc ? bsum[0][l] : bsum[1][l];
            float a0 = bias, a1 = bias, a2 = bias, a3 = bias;

            // ---- Whh dot (reads old sh[l]) with interleaved whh refill ----
            #pragma unroll
            for (int i = 0; i < NCHUNK; ++i) {
                const float4 w = whh[i];
                DOT4(w, &sh[l][0][0], 4 * i);
                whh[i] = *(const float4*)&nWhh[4 * i];
            }

            // ---- input dot ----
            if (l == 0) {
                const float4 w = w0buf;
                a0 += w.x * sx[0][0] + w.y * sx[0][1] + w.z * sx[0][2] + w.w * sx[0][3];
                a1 += w.x * sx[1][0] + w.y * sx[1][1] + w.z * sx[1][2] + w.w * sx[1][3];
                a2 += w.x * sx[2][0] + w.y * sx[2][1] + w.z * sx[2][2] + w.w * sx[2][3];
                a3 += w.x * sx[3][0] + w.y * sx[3][1] + w.z * sx[3][2] + w.w * sx[3][3];
                // refill wih for next stage (nl==1 always valid here)
                #pragma unroll
                for (int i = 0; i < NCHUNK; ++i)
                    wih[i] = *(const float4*)&nWih[4 * i];
            } else {
                if (nWih) {
                    #pragma unroll
                    for (int i = 0; i < NCHUNK; ++i) {
                        const float4 w = wih[i];
                        DOT4(w, &sh[l - 1][0][0], 4 * i);
                        wih[i] = *(const float4*)&nWih[4 * i];   // refill
                    }
                } else {
                    #pragma unroll
                    for (int i = 0; i < NCHUNK; ++i) {
                        const float4 w = wih[i];
                        DOT4(w, &sh[l - 1][0][0], 4 * i);
                    }
                    if (nW0) w0buf = *(const float4*)&nW0[0];    // next t's l0 row
                }
            }

            // ---- activation + gate exchange ----
            const float v0 = is_tanh_gate ? tanh_fast(a0) : sigm(a0);
            const float v1 = is_tanh_gate ? tanh_fast(a1) : sigm(a1);
            const float v2 = is_tanh_gate ? tanh_fast(a2) : sigm(a2);
            const float v3 = is_tanh_gate ? tanh_fast(a3) : sigm(a3);
            sg[0][g] = v0;
            sg[1][g] = v1;
            sg[2][g] = v2;
            sg[3][g] = v3;
            __syncthreads();   // gates ready

            // ---- state update ----
            {
                const float iv = sg[unb][uj];
                const float fv = sg[unb][uj + HID];
                const float gv = sg[unb][uj + 2 * HID];
                const float ov = sg[unb][uj + 3 * HID];
                const float cn = fv * sc[l][unb][uj] + iv * gv;
                const float hn = ov * tanh_fast(cn);
                sc[l][unb][uj] = cn;
                sh[l][unb][uj] = hn;
            }
            __syncthreads();   // h/c updated before next stage reads them
        }

        if (!enc) {
            const int td = t - SEQLEN;
            if (tid < NB) {
                float s = fcb[0];
                #pragma unroll
                for (int j = 0; j < HID; j += 4) {
                    const float4 wv = *(const float4*)&fcW[j];
                    const float4 hv = *(const float4*)&sh[LAYERS - 1][tid][j];
                    s += wv.x * hv.x + wv.y * hv.y + wv.z * hv.z + wv.w * hv.w;
                }
                out[(size_t)(b0 + tid) * PREDLEN + td] = s;
                sx[tid][0] = s;                       // feedback feature 0
            } else if (tid >= 64 && tid < 64 + NB * 3) {
                const int q = tid - 64;
                const int nb = q / 3, k = q % 3;
                sx[nb][k + 1] = ff[((size_t)(b0 + nb) * PREDLEN + td) * 3 + k];
            }
            // top-of-loop __syncthreads() covers these sx writes
        }
    }
}

extern "C" void kernel_launch(void* const* d_in, const int* in_sizes, int n_in,
                              void* d_out, int out_size, void* d_ws, size_t ws_size,
                              hipStream_t stream) {
    const float* x    = (const float*)d_in[0];
    const float* ff   = (const float*)d_in[1];
    const float* eW0  = (const float*)d_in[2];
    const float* eWih = (const float*)d_in[3];
    const float* eWhh = (const float*)d_in[4];
    const float* ebih = (const float*)d_in[5];
    const float* ebhh = (const float*)d_in[6];
    const float* dW0  = (const float*)d_in[7];
    const float* dWih = (const float*)d_in[8];
    const float* dWhh = (const float*)d_in[9];
    const float* dbih = (const float*)d_in[10];
    const float* dbhh = (const float*)d_in[11];
    const float* fcW  = (const float*)d_in[12];
    const float* fcb  = (const float*)d_in[13];

    lstm_s2s<<<BATCH / NB, NTHR, 0, stream>>>(
        x, ff, eW0, eWih, eWhh, ebih, ebhh,
        dW0, dWih, dWhh, dbih, dbhh, fcW, fcb, (float*)d_out);
}